// Round 1
// 439.365 us; speedup vs baseline: 1.0641x; 1.0641x over previous
//
#include <hip/hip_runtime.h>
#include <stdint.h>

#define NN 50000
#define EE 1600000
#define IN_DIMC 256
#define HIDC 128
#define EPSC 1e-5f

// counting-sort geometry
#define NB 196        // coarse buckets: dst>>8, 256 nodes/bucket (196*256 >= 50000)
#define GA 512        // phase-A blocks
#define CHUNK 3125    // EE / GA exactly

typedef unsigned short ushort_t;
typedef __attribute__((ext_vector_type(8))) short short8;
typedef __attribute__((ext_vector_type(4))) float floatx4;

static __device__ inline ushort_t f2bf(float f) {
    unsigned int u = __float_as_uint(f);
    u = u + 0x7fffu + ((u >> 16) & 1u);   // RNE
    return (ushort_t)(u >> 16);
}
static __device__ inline unsigned int pack2(float a, float b) {
    return (unsigned int)f2bf(a) | ((unsigned int)f2bf(b) << 16);
}
static __device__ inline float bf2f(unsigned int bits16) {
    return __uint_as_float(bits16 << 16);
}

// ---------------------------------------------------------------------------
// All six weight transposes + bf16 convert in ONE launch.
// Wt[n][k] = bf16(W[k][n]); W is [K][128].
// Segment 0: W_in (K=256, 32768 elems); segments 1..5: K=128 (16384 each).
// ---------------------------------------------------------------------------
__global__ __launch_bounds__(256) void tcvt_all_kernel(
    const float* __restrict__ W_in, const float* __restrict__ W_hid,
    const float* __restrict__ Wl1, const float* __restrict__ Wr1,
    const float* __restrict__ Wl2, const float* __restrict__ Wr2,
    ushort_t* __restrict__ Wt_in, ushort_t* __restrict__ Wt_hid,
    ushort_t* __restrict__ Wtl1, ushort_t* __restrict__ Wtr1,
    ushort_t* __restrict__ Wtl2, ushort_t* __restrict__ Wtr2)
{
    const int idx = blockIdx.x * 256 + threadIdx.x;
    if (idx < 32768) {
        const int n = idx >> 8;           // /256
        const int k = idx & 255;
        Wt_in[idx] = f2bf(W_in[(size_t)k * 128 + n]);
    } else if (idx < 32768 + 5 * 16384) {
        const int r = idx - 32768;
        const int seg = r / 16384;
        const int j = r - seg * 16384;
        const int n = j >> 7;
        const int k = j & 127;
        const float* W; ushort_t* Wt;
        switch (seg) {
            case 0: W = W_hid; Wt = Wt_hid; break;
            case 1: W = Wl1;  Wt = Wtl1;  break;
            case 2: W = Wr1;  Wt = Wtr1;  break;
            case 3: W = Wl2;  Wt = Wtl2;  break;
            default: W = Wr2; Wt = Wtr2;  break;
        }
        Wt[j] = f2bf(W[(size_t)k * 128 + n]);
    }
}

// ---------------------------------------------------------------------------
// MFMA GEMM v2: C[M,128] = A1@W1 (+ A2@W2) + bias, fp32 accum, bf16 inputs.
//
// Restructured: 128-row blocks (grid 391). Per 128-wide K-chunk the whole
// 128x128 B panel is staged into LDS ONCE (2 barriers per chunk total);
// A fragments go global->VGPR directly per lane (verified 16x16x32 layout:
// row = lane&15, k = ks*32 + (lane>>4)*8), prefetched 8-deep. Each wave owns
// 32 rows x 128 cols = acc[2][8]; 64 MFMAs per barrier pair (was 16).
// ---------------------------------------------------------------------------
__global__ __launch_bounds__(256) void mfma_gemm_kernel(
    const void* __restrict__ A1, const ushort_t* __restrict__ Wt1, int K1, int a1type,
    const void* __restrict__ A2, const ushort_t* __restrict__ Wt2, int K2,
    const float* __restrict__ bias, float* __restrict__ C, int M,
    const float* __restrict__ preStats, const float* __restrict__ preG,
    const float* __restrict__ preBe, float* __restrict__ outStats)
{
    __shared__ ushort_t Bs[128 * 136];                 // 34816 B, pad->136 shorts
    __shared__ __align__(16) float aArr[128], bArr[128];
    __shared__ float red_s[4][128], red_q[4][128];

    const int t    = threadIdx.x;
    const int lane = t & 63;
    const int wave = t >> 6;
    const int quad = lane >> 4;
    const int l15  = lane & 15;
    const int row0 = blockIdx.x * 128 + wave * 32;     // wave's 32 rows
    const int doAffine = (preStats != nullptr);

    if (doAffine && t < 128) {
        const float invM = 1.0f / (float)M;
        const float mean = preStats[t] * invM;
        float var = preStats[128 + t] * invM - mean * mean;
        if (var < 0.0f) var = 0.0f;
        const float s = preG[t] / sqrtf(var + EPSC);
        aArr[t] = s;
        bArr[t] = preBe[t] - mean * s;
    }
    if (doAffine) __syncthreads();

    floatx4 acc[2][8];
    #pragma unroll
    for (int i = 0; i < 2; i++)
        #pragma unroll
        for (int j = 0; j < 8; j++)
            acc[i][j] = (floatx4){0.0f, 0.0f, 0.0f, 0.0f};

    const int ksq = quad * 8;
    bool firstChunk = true;

    for (int s = 0; s < 2; s++) {
        const void*     A     = s ? A2  : A1;
        const ushort_t* Wt    = s ? Wt2 : Wt1;
        const int       K     = s ? K2  : K1;
        const int       atype = s ? 1   : a1type;
        if (A == nullptr) continue;

        for (int kc = 0; kc < K; kc += 128) {
            if (!firstChunk) __syncthreads();   // protect Bs until prior compute done
            firstChunk = false;

            // ---- stage B panel: 128 rows x 128 cols bf16 (32 KB) ----
            #pragma unroll
            for (int p = 0; p < 8; p++) {
                const int idx = p * 256 + t;    // 0..2047
                const int n   = idx >> 4;
                const int c0  = (idx & 15) * 8;
                *(uint4*)(Bs + n * 136 + c0) =
                    *(const uint4*)(Wt + (size_t)n * K + kc + c0);
            }
            __syncthreads();

            // ---- A prefetch: 2 m-tiles x 4 k-steps, per-lane fragments ----
            short8 afrag[2][4];
            if (atype == 1) {
                const ushort_t* Ab = (const ushort_t*)A;
                #pragma unroll
                for (int mt = 0; mt < 2; mt++) {
                    int gr = row0 + mt * 16 + l15;
                    if (gr > M - 1) gr = M - 1;
                    const size_t base = (size_t)gr * K + kc + ksq;
                    #pragma unroll
                    for (int ks = 0; ks < 4; ks++)
                        afrag[mt][ks] = *(const short8*)(Ab + base + ks * 32);
                }
            } else {
                const float* Af = (const float*)A;
                #pragma unroll
                for (int mt = 0; mt < 2; mt++) {
                    int gr = row0 + mt * 16 + l15;
                    if (gr > M - 1) gr = M - 1;
                    const size_t base = (size_t)gr * K + kc + ksq;
                    #pragma unroll
                    for (int ks = 0; ks < 4; ks++) {
                        float4 v0 = *(const float4*)(Af + base + ks * 32);
                        float4 v1 = *(const float4*)(Af + base + ks * 32 + 4);
                        if (doAffine && s == 0) {
                            const int k0 = ks * 32 + ksq;   // kc==0 when affine (K1=128)
                            const float4 sa0 = *(const float4*)(aArr + k0);
                            const float4 sb0 = *(const float4*)(bArr + k0);
                            const float4 sa1 = *(const float4*)(aArr + k0 + 4);
                            const float4 sb1 = *(const float4*)(bArr + k0 + 4);
                            v0.x = fmaxf(sa0.x * v0.x + sb0.x, 0.0f);
                            v0.y = fmaxf(sa0.y * v0.y + sb0.y, 0.0f);
                            v0.z = fmaxf(sa0.z * v0.z + sb0.z, 0.0f);
                            v0.w = fmaxf(sa0.w * v0.w + sb0.w, 0.0f);
                            v1.x = fmaxf(sa1.x * v1.x + sb1.x, 0.0f);
                            v1.y = fmaxf(sa1.y * v1.y + sb1.y, 0.0f);
                            v1.z = fmaxf(sa1.z * v1.z + sb1.z, 0.0f);
                            v1.w = fmaxf(sa1.w * v1.w + sb1.w, 0.0f);
                        }
                        uint4 w;
                        w.x = pack2(v0.x, v0.y);
                        w.y = pack2(v0.z, v0.w);
                        w.z = pack2(v1.x, v1.y);
                        w.w = pack2(v1.z, v1.w);
                        afrag[mt][ks] = __builtin_bit_cast(short8, w);
                    }
                }
            }

            // ---- compute: ks outer (B frags reused across both m-tiles) ----
            #pragma unroll
            for (int ks = 0; ks < 4; ks++) {
                const int ko = ks * 32 + ksq;
                short8 b[8];
                #pragma unroll
                for (int j = 0; j < 8; j++)
                    b[j] = *(const short8*)(Bs + (j * 16 + l15) * 136 + ko);
                #pragma unroll
                for (int mt = 0; mt < 2; mt++) {
                    #pragma unroll
                    for (int j = 0; j < 8; j++)
                        acc[mt][j] = __builtin_amdgcn_mfma_f32_16x16x32_bf16(
                            afrag[mt][ks], b[j], acc[mt][j], 0, 0, 0);
                }
            }
        }
    }

    // ---- epilogue: bias, C store, per-column stats ----
    float s_[8], q_[8];
    #pragma unroll
    for (int j = 0; j < 8; j++) { s_[j] = 0.0f; q_[j] = 0.0f; }

    #pragma unroll
    for (int j = 0; j < 8; j++) {
        const int col = j * 16 + l15;
        const float bv = bias[col];
        #pragma unroll
        for (int mt = 0; mt < 2; mt++) {
            const int rbase = row0 + mt * 16 + quad * 4;
            #pragma unroll
            for (int reg = 0; reg < 4; reg++) {
                const float val = acc[mt][j][reg] + bv;
                const int r_ = rbase + reg;
                if (r_ < M) {
                    C[(size_t)r_ * HIDC + col] = val;
                    s_[j] += val;
                    q_[j] += val * val;
                }
            }
        }
    }
    #pragma unroll
    for (int j = 0; j < 8; j++) {
        s_[j] += __shfl_xor(s_[j], 16, 64);
        s_[j] += __shfl_xor(s_[j], 32, 64);
        q_[j] += __shfl_xor(q_[j], 16, 64);
        q_[j] += __shfl_xor(q_[j], 32, 64);
    }
    if (quad == 0) {
        #pragma unroll
        for (int j = 0; j < 8; j++) {
            red_s[wave][j * 16 + l15] = s_[j];
            red_q[wave][j * 16 + l15] = q_[j];
        }
    }
    __syncthreads();
    if (t < 128) {
        const float S = red_s[0][t] + red_s[1][t] + red_s[2][t] + red_s[3][t];
        const float Q = red_q[0][t] + red_q[1][t] + red_q[2][t] + red_q[3][t];
        atomicAdd(&outStats[t], S);
        atomicAdd(&outStats[128 + t], Q);
    }
}

// ---------------------------------------------------------------------------
// BN apply: dst fp32 (optional) and/or dst bf16 (optional), + optional relu
// ---------------------------------------------------------------------------
__global__ __launch_bounds__(256) void bn_apply_kernel(
    const float* __restrict__ src, float* __restrict__ dstF,
    ushort_t* __restrict__ dstB, const float* __restrict__ stats,
    const float* __restrict__ gamma, const float* __restrict__ beta,
    int relu, int M)
{
    __shared__ float sc[128], sh[128];
    const int t = threadIdx.x;
    if (t < 128) {
        const float invM = 1.0f / (float)M;
        const float mean = stats[t] * invM;
        float var = stats[128 + t] * invM - mean * mean;
        if (var < 0.0f) var = 0.0f;
        const float s = gamma[t] / sqrtf(var + EPSC);
        sc[t] = s;
        sh[t] = beta[t] - mean * s;
    }
    __syncthreads();

    const int total4 = M * HIDC / 4;
    for (int i = blockIdx.x * 256 + t; i < total4; i += gridDim.x * 256) {
        float4 v = ((const float4*)src)[i];
        const int c = (i * 4) & 127;
        v.x = v.x * sc[c]     + sh[c];
        v.y = v.y * sc[c + 1] + sh[c + 1];
        v.z = v.z * sc[c + 2] + sh[c + 2];
        v.w = v.w * sc[c + 3] + sh[c + 3];
        if (relu) {
            v.x = fmaxf(v.x, 0.0f); v.y = fmaxf(v.y, 0.0f);
            v.z = fmaxf(v.z, 0.0f); v.w = fmaxf(v.w, 0.0f);
        }
        if (dstF) ((float4*)dstF)[i] = v;
        if (dstB) {
            uint2 w;
            w.x = pack2(v.x, v.y);
            w.y = pack2(v.z, v.w);
            *(uint2*)(dstB + (size_t)i * 4) = w;
        }
    }
}

// ---------------------------------------------------------------------------
// CSR build — atomic-free two-level counting sort (no stability needed: mean
// aggregation is order-invariant within a dst).
// ---------------------------------------------------------------------------
__global__ __launch_bounds__(256) void bucket_hist_kernel(
    const int* __restrict__ dstArr, int* __restrict__ hist2D)
{
    __shared__ int hist[NB];
    const int t = threadIdx.x;
    for (int i = t; i < NB; i += 256) hist[i] = 0;
    __syncthreads();
    const int e0 = blockIdx.x * CHUNK;
    const int e1 = e0 + CHUNK;   // EE = GA*CHUNK exactly
    for (int e = e0 + t; e < e1; e += 256)
        atomicAdd(&hist[dstArr[e] >> 8], 1);
    __syncthreads();
    for (int i = t; i < NB; i += 256)
        hist2D[(size_t)i * GA + blockIdx.x] = hist[i];
}

__global__ __launch_bounds__(256) void bucket_offsets_kernel(
    int* __restrict__ hist2D, int* __restrict__ bucketBase, int* __restrict__ rowp)
{
    __shared__ int wtot[4];
    const int t = threadIdx.x;
    int tot = 0;
    if (t < NB) {
        int4* p = (int4*)(hist2D + (size_t)t * GA);
        int s = 0;
        for (int i = 0; i < GA / 4; i++) {
            int4 h = p[i];
            int4 o;
            o.x = s; s += h.x;
            o.y = s; s += h.y;
            o.z = s; s += h.z;
            o.w = s; s += h.w;
            p[i] = o;
        }
        tot = s;
    }
    // exclusive scan of tot across 256 threads
    const int lane = t & 63, w = t >> 6;
    int x = tot;
    #pragma unroll
    for (int off = 1; off < 64; off <<= 1) {
        const int y = __shfl_up(x, off);
        if (lane >= off) x += y;
    }
    if (lane == 63) wtot[w] = x;
    __syncthreads();
    int woff = 0;
    #pragma unroll
    for (int j = 0; j < 4; j++) if (j < w) woff += wtot[j];
    const int excl = x + woff - tot;
    if (t < NB) bucketBase[t] = excl;
    if (t == 0) { bucketBase[NB] = EE; rowp[NN] = EE; }
}

__global__ __launch_bounds__(256) void bucket_scatter_kernel(
    const int* __restrict__ srcArr, const int* __restrict__ dstArr,
    const int* __restrict__ hist2D, const int* __restrict__ bucketBase,
    int2* __restrict__ ebuf)
{
    __shared__ int cur[NB];
    const int t = threadIdx.x;
    for (int i = t; i < NB; i += 256)
        cur[i] = bucketBase[i] + hist2D[(size_t)i * GA + blockIdx.x];
    __syncthreads();
    const int e0 = blockIdx.x * CHUNK;
    const int e1 = e0 + CHUNK;
    for (int e = e0 + t; e < e1; e += 256) {
        const int d = dstArr[e];
        const int s = srcArr[e];
        const int p = atomicAdd(&cur[d >> 8], 1);
        ebuf[p] = make_int2(s, d);
    }
}

__global__ __launch_bounds__(256) void fine_sort_kernel(
    const int2* __restrict__ ebuf, const int* __restrict__ bucketBase,
    int* __restrict__ rowp, int* __restrict__ col)
{
    __shared__ int cnt[256];
    __shared__ int wtot[4];
    const int b = blockIdx.x;
    const int t = threadIdx.x;
    const int bb0 = bucketBase[b];
    const int bb1 = bucketBase[b + 1];
    cnt[t] = 0;
    __syncthreads();
    for (int e = bb0 + t; e < bb1; e += 256)
        atomicAdd(&cnt[ebuf[e].y & 255], 1);
    __syncthreads();
    // exclusive scan of cnt[256]
    const int lane = t & 63, w = t >> 6;
    const int v = cnt[t];
    int x = v;
    #pragma unroll
    for (int off = 1; off < 64; off <<= 1) {
        const int y = __shfl_up(x, off);
        if (lane >= off) x += y;
    }
    if (lane == 63) wtot[w] = x;
    __syncthreads();
    int woff = 0;
    #pragma unroll
    for (int j = 0; j < 4; j++) if (j < w) woff += wtot[j];
    const int excl = x + woff - v;
    const int node = b * 256 + t;
    if (node < NN) rowp[node] = bb0 + excl;
    __syncthreads();
    cnt[t] = excl;     // reuse as local cursor
    __syncthreads();
    for (int e = bb0 + t; e < bb1; e += 256) {
        const int2 sd = ebuf[e];
        const int p = atomicAdd(&cnt[sd.y & 255], 1);
        col[bb0 + p] = sd.x;
    }
}

// ---------------------------------------------------------------------------
// Mean aggregation over bf16 features: one wave per node, 2 cols/lane (4 B).
// Wave-uniform CSR bounds in SGPRs; unroll 8 keeps 8 gathers in flight.
// ---------------------------------------------------------------------------
__global__ __launch_bounds__(256) void agg_kernel(
    const ushort_t* __restrict__ F, const int* __restrict__ row_ptr,
    const int* __restrict__ col, ushort_t* __restrict__ Mout)
{
    const int lane = threadIdx.x & 63;
    const int wave = blockIdx.x * (blockDim.x >> 6) + (threadIdx.x >> 6);
    const int nwaves = gridDim.x * (blockDim.x >> 6);
    const int coff = lane * 2;

    for (int n = wave; n < NN; n += nwaves) {
        const int b = __builtin_amdgcn_readfirstlane(row_ptr[n]);
        const int e = __builtin_amdgcn_readfirstlane(row_ptr[n + 1]);
        const int deg = e - b;
        float accx = 0.0f, accy = 0.0f;
        int j = b;
        for (; j + 8 <= e; j += 8) {
            const int s0 = col[j + 0];
            const int s1 = col[j + 1];
            const int s2 = col[j + 2];
            const int s3 = col[j + 3];
            const int s4 = col[j + 4];
            const int s5 = col[j + 5];
            const int s6 = col[j + 6];
            const int s7 = col[j + 7];
            const unsigned int v0 = *(const unsigned int*)(F + (size_t)s0 * HIDC + coff);
            const unsigned int v1 = *(const unsigned int*)(F + (size_t)s1 * HIDC + coff);
            const unsigned int v2 = *(const unsigned int*)(F + (size_t)s2 * HIDC + coff);
            const unsigned int v3 = *(const unsigned int*)(F + (size_t)s3 * HIDC + coff);
            const unsigned int v4 = *(const unsigned int*)(F + (size_t)s4 * HIDC + coff);
            const unsigned int v5 = *(const unsigned int*)(F + (size_t)s5 * HIDC + coff);
            const unsigned int v6 = *(const unsigned int*)(F + (size_t)s6 * HIDC + coff);
            const unsigned int v7 = *(const unsigned int*)(F + (size_t)s7 * HIDC + coff);
            accx += bf2f(v0 & 0xffffu) + bf2f(v1 & 0xffffu) + bf2f(v2 & 0xffffu)
                  + bf2f(v3 & 0xffffu) + bf2f(v4 & 0xffffu) + bf2f(v5 & 0xffffu)
                  + bf2f(v6 & 0xffffu) + bf2f(v7 & 0xffffu);
            accy += bf2f(v0 >> 16) + bf2f(v1 >> 16) + bf2f(v2 >> 16)
                  + bf2f(v3 >> 16) + bf2f(v4 >> 16) + bf2f(v5 >> 16)
                  + bf2f(v6 >> 16) + bf2f(v7 >> 16);
        }
        for (; j < e; j++) {
            const int s = col[j];
            const unsigned int v = *(const unsigned int*)(F + (size_t)s * HIDC + coff);
            accx += bf2f(v & 0xffffu);
            accy += bf2f(v >> 16);
        }
        const float inv = 1.0f / (float)(deg > 1 ? deg : 1);
        *(unsigned int*)(Mout + (size_t)n * HIDC + coff) =
            pack2(accx * inv, accy * inv);
    }
}

// ---------------------------------------------------------------------------
extern "C" void kernel_launch(void* const* d_in, const int* in_sizes, int n_in,
                              void* d_out, int out_size, void* d_ws, size_t ws_size,
                              hipStream_t stream)
{
    const float* x     = (const float*)d_in[0];
    const int*   ei    = (const int*)  d_in[1];
    const float* W_in  = (const float*)d_in[2];
    const float* b_in  = (const float*)d_in[3];
    const float* g1    = (const float*)d_in[4];
    const float* be1   = (const float*)d_in[5];
    const float* W_hid = (const float*)d_in[6];
    const float* b_hid = (const float*)d_in[7];
    const float* g2    = (const float*)d_in[8];
    const float* be2   = (const float*)d_in[9];
    const float* Wl1   = (const float*)d_in[10];
    const float* bl1   = (const float*)d_in[11];
    const float* Wr1   = (const float*)d_in[12];
    const float* g3    = (const float*)d_in[13];
    const float* be3   = (const float*)d_in[14];
    const float* Wl2   = (const float*)d_in[15];
    const float* bl2   = (const float*)d_in[16];
    const float* Wr2   = (const float*)d_in[17];
    const float* g4    = (const float*)d_in[18];
    const float* be4   = (const float*)d_in[19];

    const int* srcArr = ei;        // edge_index[0]
    const int* dstArr = ei + EE;   // edge_index[1]

    char* ws = (char*)d_ws;
    float*    bufA      = (float*)ws;    ws += (size_t)NN * HIDC * sizeof(float);
    float*    bufB      = (float*)ws;    ws += (size_t)NN * HIDC * sizeof(float);
    ushort_t* featB16   = (ushort_t*)ws; ws += (size_t)NN * HIDC * sizeof(ushort_t);
    ushort_t* o3B16     = (ushort_t*)ws; ws += (size_t)NN * HIDC * sizeof(ushort_t);
    ushort_t* aggB16    = (ushort_t*)ws; ws += (size_t)NN * HIDC * sizeof(ushort_t);
    float*    stats     = (float*)ws;    ws += 4 * 256 * sizeof(float);
    int*      hist2D    = (int*)ws;      ws += (size_t)NB * GA * sizeof(int);
    int*      bucketBase= (int*)ws;      ws += (NB + 4) * sizeof(int);
    int*      rowp      = (int*)ws;      ws += (size_t)(NN + 4) * sizeof(int);
    int*      colIdx    = (int*)ws;      ws += (size_t)EE * sizeof(int);
    int2*     ebuf      = (int2*)ws;     ws += (size_t)EE * sizeof(int2);
    ushort_t* Wt_in     = (ushort_t*)ws; ws += 128 * 256 * sizeof(ushort_t);
    ushort_t* Wt_hid    = (ushort_t*)ws; ws += 128 * 128 * sizeof(ushort_t);
    ushort_t* Wtl1      = (ushort_t*)ws; ws += 128 * 128 * sizeof(ushort_t);
    ushort_t* Wtr1      = (ushort_t*)ws; ws += 128 * 128 * sizeof(ushort_t);
    ushort_t* Wtl2      = (ushort_t*)ws; ws += 128 * 128 * sizeof(ushort_t);
    ushort_t* Wtr2      = (ushort_t*)ws; ws += 128 * 128 * sizeof(ushort_t);

    float* out0 = (float*)d_out;             // feat  [NN*HID] fp32
    float* out1 = out0 + (size_t)NN * HIDC;  // out   [NN*HID] fp32

    // zero: stats only (counting sort is store-based, nothing else needs init)
    hipMemsetAsync(stats, 0, 4 * 256 * sizeof(float), stream);

    // weight transpose + bf16 convert (one launch, 448 blocks)
    tcvt_all_kernel<<<448, 256, 0, stream>>>(W_in, W_hid, Wl1, Wr1, Wl2, Wr2,
                                             Wt_in, Wt_hid, Wtl1, Wtr1, Wtl2, Wtr2);

    // CSR build — atomic-free counting sort
    bucket_hist_kernel<<<GA, 256, 0, stream>>>(dstArr, hist2D);
    bucket_offsets_kernel<<<1, 256, 0, stream>>>(hist2D, bucketBase, rowp);
    bucket_scatter_kernel<<<GA, 256, 0, stream>>>(srcArr, dstArr, hist2D,
                                                  bucketBase, ebuf);
    fine_sort_kernel<<<NB, 256, 0, stream>>>(ebuf, bucketBase, rowp, colIdx);

    const int gemmGrid = (NN + 127) / 128;   // 391

    // stage 1: input linear (x fp32, K=256) -> bufA fp32 + stats0
    mfma_gemm_kernel<<<gemmGrid, 256, 0, stream>>>(
        x, Wt_in, IN_DIMC, 0, nullptr, nullptr, 0,
        b_in, bufA, NN, nullptr, nullptr, nullptr, stats + 0);

    // stage 2: hidden linear, BN1+relu fused on A-load -> bufB fp32 + stats1
    mfma_gemm_kernel<<<gemmGrid, 256, 0, stream>>>(
        bufA, Wt_hid, HIDC, 0, nullptr, nullptr, 0,
        b_hid, bufB, NN, stats + 0, g1, be1, stats + 256);

    // BN2+relu -> out0 (fp32) + featB16 (bf16)
    bn_apply_kernel<<<1024, 256, 0, stream>>>(bufB, out0, featB16,
                                              stats + 256, g2, be2, 1, NN);

    // stage 3: SAGE1
    agg_kernel<<<4096, 256, 0, stream>>>(featB16, rowp, colIdx, aggB16);
    mfma_gemm_kernel<<<gemmGrid, 256, 0, stream>>>(
        aggB16, Wtl1, HIDC, 1, featB16, Wtr1, HIDC,
        bl1, bufA, NN, nullptr, nullptr, nullptr, stats + 512);

    // BN3 -> o3B16 (bf16 only)
    bn_apply_kernel<<<1024, 256, 0, stream>>>(bufA, nullptr, o3B16,
                                              stats + 512, g3, be3, 0, NN);

    // stage 4: SAGE2
    agg_kernel<<<4096, 256, 0, stream>>>(o3B16, rowp, colIdx, aggB16);
    mfma_gemm_kernel<<<gemmGrid, 256, 0, stream>>>(
        aggB16, Wtl2, HIDC, 1, o3B16, Wtr2, HIDC,
        bl2, bufB, NN, nullptr, nullptr, nullptr, stats + 768);

    // BN4 -> out1 (fp32)
    bn_apply_kernel<<<1024, 256, 0, stream>>>(bufB, out1, nullptr,
                                              stats + 768, g4, be4, 0, NN);
}